// Round 3
// baseline (683.557 us; speedup 1.0000x reference)
//
#include <hip/hip_runtime.h>
#include <math.h>

// Tril2Diff: out[b] = L @ L^T where L is 128x128 lower-triangular scattered
// from x[b] (8256 tril values), diagonal replaced by log1p(exp(d)+1e-12).
//
// Memory-bound target: ~672 MB real HBM traffic -> ~107us floor.
// R1 killed the VALU bottleneck (table-driven scatter); R2 raised occupancy
// (swizzled 32KB LDS, 5 blocks/CU). R3 removes the per-block serial critical
// path: each block now pipelines NB=4 batches:
//  - LDS zeroed ONCE (scatter only writes lower triangle; upper zeros persist)
//  - scatter-offset table loaded ONCE into regs (batch-invariant)
//  - batch n+1's x prefetched into regs during batch n's MFMA
//  - batch n's stores issue interleaved with batch n+1's scatter

#define DIM        128
#define NTRIL      8256          // 128*129/2
#define ROW_BYTES  256           // bf16 row, no pad; XOR swizzle kills conflicts
#define NB         4             // batches per block

typedef __bf16 bf16x8 __attribute__((ext_vector_type(8)));
typedef float  f32x16 __attribute__((ext_vector_type(16)));

// ---- compile-time scatter table: flat tril index -> swizzled LDS byte offset ----
struct RcTab { unsigned short off[NTRIL]; };
static constexpr RcTab make_tab() {
    RcTab t{};
    int idx = 0;
    for (int r = 0; r < DIM; ++r)
        for (int c = 0; c <= r; ++c)
            t.off[idx++] = (unsigned short)((r * ROW_BYTES + c * 2) ^ ((r & 7) << 4));
    return t;
}
__device__ const RcTab TBL = make_tab();

__device__ __forceinline__ int rowbase(int r) {   // swizzled base byte of row r
    return (r << 8) ^ ((r & 7) << 4);
}

__global__ __launch_bounds__(256) void tril2diff_kernel(
    const float* __restrict__ x, float* __restrict__ out)
{
    __shared__ alignas(16) __bf16 Lsh[DIM * ROW_BYTES / 2];   // 32768 B exactly

    const int tid = threadIdx.x;
    const int b0  = blockIdx.x * NB;

    // ---- batch-invariant scatter offsets: load once, keep in regs ----
    ushort4 o[8], ot;
    #pragma unroll
    for (int i = 0; i < 8; ++i)
        o[i] = *(const ushort4*)(TBL.off + (tid + i * 256) * 4);
    if (tid < 16)                         // tail: 8256/4 = 2064 = 8*256 + 16
        ot = *(const ushort4*)(TBL.off + (2048 + tid) * 4);

    // ---- prefetch batch 0 (latency hides under zero-fill) ----
    float4 v[8], vt;
    float  dvx;
    {
        const float* xb = x + (size_t)b0 * NTRIL;
        #pragma unroll
        for (int i = 0; i < 8; ++i)
            v[i] = *(const float4*)(xb + (tid + i * 256) * 4);
        if (tid < 16)
            vt = *(const float4*)(xb + (2048 + tid) * 4);
        if (tid < DIM)
            dvx = xb[(tid * (tid + 1)) / 2 + tid];
    }

    // ---- zero LDS ONCE: scatter only writes lower triangle, so the upper
    //      triangle (and its swizzled image) stays zero across all NB batches
    uint4* lz4 = (uint4*)Lsh;
    #pragma unroll
    for (int i = 0; i < 8; ++i)
        lz4[tid + i * 256] = uint4{0u, 0u, 0u, 0u};
    __syncthreads();

    // ---- per-wave MFMA geometry (loop-invariant) ----
    const int lane = tid & 63;
    const int wv   = tid >> 6;
    const int i0   = (wv >> 1) * 64;
    const int j0   = (wv & 1) * 64;
    const int cl   = lane & 31;
    const int hh   = lane >> 5;
    const int kb   = hh * 16;
    const int ba0 = rowbase(i0      + cl);
    const int ba1 = rowbase(i0 + 32 + cl);
    const int bb0 = rowbase(j0      + cl);
    const int bb1 = rowbase(j0 + 32 + cl);

    char*       lbw = (char*)Lsh;
    const char* lb  = (const char*)Lsh;

    for (int n = 0; n < NB; ++n) {
        // ---- scatter regs -> L (bf16), table-driven (swizzle baked in) ----
        #pragma unroll
        for (int i = 0; i < 8; ++i) {
            *(__bf16*)(lbw + o[i].x) = (__bf16)v[i].x;
            *(__bf16*)(lbw + o[i].y) = (__bf16)v[i].y;
            *(__bf16*)(lbw + o[i].z) = (__bf16)v[i].z;
            *(__bf16*)(lbw + o[i].w) = (__bf16)v[i].w;
        }
        if (tid < 16) {
            *(__bf16*)(lbw + ot.x) = (__bf16)vt.x;
            *(__bf16*)(lbw + ot.y) = (__bf16)vt.y;
            *(__bf16*)(lbw + ot.z) = (__bf16)vt.z;
            *(__bf16*)(lbw + ot.w) = (__bf16)vt.w;
        }
        float dv;
        if (tid < DIM)                      // softplus overlaps others' scatter
            dv = log1pf(expf(dvx) + 1e-12f);
        __syncthreads();

        // ---- overwrite diagonal (tiny, convergent) ----
        if (tid < DIM)
            *(__bf16*)(lbw + ((tid * ROW_BYTES + tid * 2) ^ ((tid & 7) << 4))) = (__bf16)dv;
        __syncthreads();

        // ---- prefetch batch n+1 into regs (overlaps MFMA + stores) ----
        if (n + 1 < NB) {
            const float* xb = x + (size_t)(b0 + n + 1) * NTRIL;
            #pragma unroll
            for (int i = 0; i < 8; ++i)
                v[i] = *(const float4*)(xb + (tid + i * 256) * 4);
            if (tid < 16)
                vt = *(const float4*)(xb + (2048 + tid) * 4);
            if (tid < DIM)
                dvx = xb[(tid * (tid + 1)) / 2 + tid];
        }

        // ---- C = L * L^T via 32x32x16 bf16 MFMA ----
        // wave w owns 64x64 quadrant (w>>1, w&1). L[.,k]==0 for k>=64 in rows
        // 0..63 -> only quadrant (1,1) needs k-steps 4..7.
        f32x16 acc00 = {0}, acc01 = {0}, acc10 = {0}, acc11 = {0};

#define MFMA_STEP(ks)                                                          \
    {                                                                          \
        const int koff = (ks) * 32 + kb;                                       \
        bf16x8 a0 = *(const bf16x8*)(lb + (ba0 ^ koff));                       \
        bf16x8 a1 = *(const bf16x8*)(lb + (ba1 ^ koff));                       \
        bf16x8 b0 = *(const bf16x8*)(lb + (bb0 ^ koff));                       \
        bf16x8 b1 = *(const bf16x8*)(lb + (bb1 ^ koff));                       \
        acc00 = __builtin_amdgcn_mfma_f32_32x32x16_bf16(a0, b0, acc00, 0, 0, 0); \
        acc01 = __builtin_amdgcn_mfma_f32_32x32x16_bf16(a0, b1, acc01, 0, 0, 0); \
        acc10 = __builtin_amdgcn_mfma_f32_32x32x16_bf16(a1, b0, acc10, 0, 0, 0); \
        acc11 = __builtin_amdgcn_mfma_f32_32x32x16_bf16(a1, b1, acc11, 0, 0, 0); \
    }

        #pragma unroll
        for (int ks = 0; ks < 4; ++ks)
            MFMA_STEP(ks);
        if (wv == 3) {
            #pragma unroll
            for (int ks = 4; ks < 8; ++ks)
                MFMA_STEP(ks);
        }
#undef MFMA_STEP

        __syncthreads();   // all ds_reads of L done before next scatter overwrites

        // ---- store batch n (overlaps next iteration's scatter) ----
        // C/D layout: col=lane&31, row=(reg&3)+8*(reg>>2)+4*(lane>>5).
        // Each 32-lane half-wave writes 128 contiguous bytes per store.
        float* ob = out + (size_t)(b0 + n) * (DIM * DIM);
        #pragma unroll
        for (int reg = 0; reg < 16; ++reg) {
            const int row = (reg & 3) + 8 * (reg >> 2) + 4 * hh;
            ob[(i0      + row) * DIM + j0      + cl] = acc00[reg];
            ob[(i0      + row) * DIM + j0 + 32 + cl] = acc01[reg];
            ob[(i0 + 32 + row) * DIM + j0      + cl] = acc10[reg];
            ob[(i0 + 32 + row) * DIM + j0 + 32 + cl] = acc11[reg];
        }
    }
}

extern "C" void kernel_launch(void* const* d_in, const int* in_sizes, int n_in,
                              void* d_out, int out_size, void* d_ws, size_t ws_size,
                              hipStream_t stream) {
    const float* x = (const float*)d_in[0];
    float* out = (float*)d_out;
    const int batch = in_sizes[0] / NTRIL;   // 8192
    tril2diff_kernel<<<batch / NB, 256, 0, stream>>>(x, out);
}